// Round 1
// 26950.854 us; speedup vs baseline: 1.0513x; 1.0513x over previous
//
#include <hip/hip_runtime.h>
#include <stdint.h>

// Transducer greedy decode, persistent 3-stage pipeline.
// R5: handoff latency attack. R4's single shared epoch line per handoff was
// spin-polled by 63-160 blocks (agent-scope loads) -> same-LLC-line request
// serialization inflated the line RT to multi-us, delaying BOTH epoch
// publication (store queues behind the poll storm) and discovery. Counters:
// VALUBusy 7.6% => ~2.1us/step of real work vs 28.2us/step wall. Fix: direct
// producer->consumer multicast flags. Each (consumer,producer) pair owns a
// private 16B slot: producer fans out its flag (1 store/consumer), consumer
// polls its OWN slots (1 lane/slot). Every polled line: 1 polling block,
// <=8 writers. Also removes the aggregator->epoch republish round-trip.
// Kept from R4: ~124KB LDS forces 1 block/CU; barrier-drains-vmcnt before
// flag store (release); A computes Wtn.tn_t BEFORE waiting for h; C stashes
// h in LDS (stride 648) reused by both Whh passes.
// Stages (224 blk x 256 thr, 1 blk/CU): A(80): z=tanh(Wtn.x+Wpn.h+bj)
// L(64): logits -> per-block argmax/sumexp slots (zero-RMW)
// C(80): Whh.h + slot-reduce + decode + LSTM elementwise.
// Chain: C(t-1) -> A(t) -> L(t) -> C-tail(t).

typedef unsigned long long u64;
typedef uint32_t u32;

#define TT 1000
#define DD 640
#define GG 2560
#define VV 1024

#define NA 80
#define NL 64
#define NC 80
#define NBLK (NA + NL + NC) // 224

// ws layout (float offsets)
static constexpr size_t OFF_WTN  = 0;                      // 640x640  WT4
static constexpr size_t OFF_WPN  = OFF_WTN  + 409600;
static constexpr size_t OFF_WHH  = OFF_WPN  + 409600;      // 2560x640
static constexpr size_t OFF_WOUT = OFF_WHH  + 1638400;     // 1024x640
static constexpr size_t OFF_P    = OFF_WOUT + 655360;      // 1024x2560
static constexpr size_t OFF_XH   = OFF_P    + 2621440;     // h [2 par][32][640]
static constexpr size_t OFF_XZ   = OFF_XH   + 40960;       // z [32][640]
static constexpr size_t OFF_SC   = OFF_XZ   + 20480;       // score[32]
static constexpr size_t OFF_LKEY = OFF_SC   + 32;          // u64 [32][64] slots
static constexpr size_t OFF_LSE  = OFF_LKEY + 4096;        // f32 [32][64] slots
// R5 multicast flags: [consumer][producer] slots, 4 ints (16B) per slot.
// FC: producers = 80 C blocks, consumers = 80 A + 80 C (cons idx: A=bid, C=80+cb)
// FA: producers = 80 A blocks, consumers = 64 L
// FL: producers = 64 L blocks, consumers = 80 C
static constexpr size_t OFF_MCFC = OFF_LSE  + 2048;        // int[160][80][4]
static constexpr size_t OFF_MCFA = OFF_MCFC + 51200;       // int[64][80][4]
static constexpr size_t OFF_MCFL = OFF_MCFA + 20480;       // int[80][64][4]
static constexpr size_t OFF_END  = OFF_MCFL + 20480;       // ~23.6 MB

__device__ __forceinline__ float sigf(float x) { return 1.0f / (1.0f + expf(-x)); }

__device__ __forceinline__ u32 ordf(float f) {
  u32 u = __float_as_uint(f);
  return (u & 0x80000000u) ? ~u : (u | 0x80000000u);
}

// ---- coherent (LLC) accesses: bypass L1/L2, no fences (R3/R4-validated) ----
__device__ __forceinline__ void cstore2(float* p, float a, float b) {
  u64 v = ((u64)__float_as_uint(b) << 32) | (u64)__float_as_uint(a);
  __hip_atomic_store((u64*)p, v, __ATOMIC_RELAXED, __HIP_MEMORY_SCOPE_AGENT);
}
__device__ __forceinline__ float2 cload2(const float* p) {
  u64 v = __hip_atomic_load((const u64*)p, __ATOMIC_RELAXED, __HIP_MEMORY_SCOPE_AGENT);
  return make_float2(__uint_as_float((u32)v), __uint_as_float((u32)(v >> 32)));
}
__device__ __forceinline__ u64 cloadu64(const u64* p) {
  return __hip_atomic_load(p, __ATOMIC_RELAXED, __HIP_MEMORY_SCOPE_AGENT);
}
__device__ __forceinline__ void cstoreu64(u64* p, u64 v) {
  __hip_atomic_store(p, v, __ATOMIC_RELAXED, __HIP_MEMORY_SCOPE_AGENT);
}
__device__ __forceinline__ float cloadf(const float* p) {
  return __hip_atomic_load(p, __ATOMIC_RELAXED, __HIP_MEMORY_SCOPE_AGENT);
}
__device__ __forceinline__ void cstoref(float* p, float v) {
  __hip_atomic_store(p, v, __ATOMIC_RELAXED, __HIP_MEMORY_SCOPE_AGENT);
}

// consumer: poll own private slots, one lane per producer. Each polled line
// is touched by exactly one block -> no cross-block poll contention.
__device__ __forceinline__ void wait_mc(const int* mc, int nprod, int target) {
  if ((int)threadIdx.x < nprod) {
    while (__hip_atomic_load(mc + threadIdx.x * 4, __ATOMIC_RELAXED,
                             __HIP_MEMORY_SCOPE_AGENT) < target)
      __builtin_amdgcn_s_sleep(2);
  }
  __syncthreads();
}
// producer: barrier drains all waves' vmcnt (data stores at LLC), then fan
// the flag out to every consumer's private slot (one store per thread).
__device__ __forceinline__ void publish_mc(int* mc, int ncons, int nprod,
                                           int myprod, int val) {
  __syncthreads();
  if ((int)threadIdx.x < ncons)
    __hip_atomic_store(mc + ((size_t)threadIdx.x * nprod + myprod) * 4, val,
                       __ATOMIC_RELAXED, __HIP_MEMORY_SCOPE_AGENT);
}

__device__ __forceinline__ void fma4(float& a, const float4 w, const float4 x) {
  a = fmaf(w.x, x.x, fmaf(w.y, x.y, fmaf(w.z, x.z, fmaf(w.w, x.w, a))));
}
__device__ __forceinline__ void fma22(float& a, const float4 w, const float2 xa,
                                      const float2 xb) {
  a = fmaf(w.x, xa.x, fmaf(w.y, xa.y, fmaf(w.z, xb.x, fmaf(w.w, xb.y, a))));
}

// ---- setup kernels ----

// W[j][d] (row-major, K=640) -> WT4: float4 at (d/4)*J + j holds W[j][4q..4q+3]
__global__ __launch_bounds__(256) void k_wt4(const float* __restrict__ W,
                                             float* __restrict__ WT4, int J) {
  __shared__ float tile[64][65];
  int nj = J >> 6;
  int tj = blockIdx.x % nj, tk = blockIdx.x / nj;
  int jb = tj << 6, kb = tk << 6;
  for (int i = threadIdx.x; i < 4096; i += 256) {
    int d = i & 63, j = i >> 6;
    tile[j][d] = W[(size_t)(jb + j) * DD + (kb + d)];
  }
  __syncthreads();
  for (int i = threadIdx.x; i < 1024; i += 256) {
    int j = i & 63, q = i >> 6;
    float4 v = make_float4(tile[j][q * 4], tile[j][q * 4 + 1], tile[j][q * 4 + 2],
                           tile[j][q * 4 + 3]);
    ((float4*)WT4)[(size_t)((kb >> 2) + q) * J + (jb + j)] = v;
  }
}

// P[v][g] = sum_d E[v][d] * Wih[g][d]
__global__ __launch_bounds__(256) void k_pgemm(const float* __restrict__ E,
                                               const float* __restrict__ Wih,
                                               float* __restrict__ P) {
  __shared__ float As[16][65], Bs[16][65];
  int vt = blockIdx.x & 15, gt = blockIdx.x >> 4;
  int vb = vt << 6, gb = gt << 6;
  int tv = threadIdx.x & 15, tg = threadIdx.x >> 4;
  float acc[4][4] = {};
  for (int kb = 0; kb < DD; kb += 16) {
    for (int i = threadIdx.x; i < 1024; i += 256) {
      int k = i & 15, x = i >> 4;
      As[k][x] = E[(size_t)(vb + x) * DD + kb + k];
      Bs[k][x] = Wih[(size_t)(gb + x) * DD + kb + k];
    }
    __syncthreads();
#pragma unroll
    for (int k = 0; k < 16; ++k) {
      float av[4], bv[4];
#pragma unroll
      for (int i = 0; i < 4; ++i) av[i] = As[k][tv * 4 + i];
#pragma unroll
      for (int j = 0; j < 4; ++j) bv[j] = Bs[k][tg * 4 + j];
#pragma unroll
      for (int i = 0; i < 4; ++i)
#pragma unroll
        for (int j = 0; j < 4; ++j) acc[i][j] = fmaf(av[i], bv[j], acc[i][j]);
    }
    __syncthreads();
  }
#pragma unroll
  for (int i = 0; i < 4; ++i)
#pragma unroll
    for (int j = 0; j < 4; ++j)
      P[(size_t)(vb + tv * 4 + i) * GG + gb + tg * 4 + j] = acc[i][j];
}

// initial LSTM step: x0=E[0], h0=c0=0 -> h1 identical for all b; XH parity 0.
// Also zeroes the multicast flag region (plain stores; kernel-boundary L2
// flush makes them LLC-visible before k_decode polls -- R4-validated pattern).
__global__ __launch_bounds__(256) void k_init(float* __restrict__ ws,
                                              const float* __restrict__ bl) {
  const float* P = ws + OFF_P;
  float* XH0 = ws + OFF_XH;
  int tid = blockIdx.x * 256 + threadIdx.x;
  if (tid < DD) {
    int j = tid;
    float gi = P[j] + bl[j];
    float gg = P[1280 + j] + bl[1280 + j];
    float go = P[1920 + j] + bl[1920 + j];
    float c1 = sigf(gi) * tanhf(gg);
    float h1 = sigf(go) * tanhf(c1);
    for (int b = 0; b < 32; ++b) XH0[b * DD + j] = h1;
  }
  int* mc = (int*)(ws + OFF_MCFC);
  for (int i = tid; i < 92160; i += 1024) mc[i] = 0; // 51200+20480+20480 ints
}

// ---- persistent decode ----
__global__ __launch_bounds__(256, 1) void k_decode(float* __restrict__ ws,
                                                   const float* __restrict__ tn,
                                                   const float* __restrict__ bl,
                                                   const float* __restrict__ bj,
                                                   const float* __restrict__ bo,
                                                   float* __restrict__ out) {
  const float* WTN = ws + OFF_WTN;
  const float* WPN = ws + OFF_WPN;
  const float* WHH = ws + OFF_WHH;
  const float* WOUT = ws + OFF_WOUT;
  const float* P = ws + OFF_P;
  float* XH = ws + OFF_XH;
  float* XZ = ws + OFF_XZ;
  float* SCg = ws + OFF_SC;
  u64* LKEY = (u64*)(ws + OFF_LKEY);
  float* LSE = ws + OFF_LSE;
  int* MCFC = (int*)(ws + OFF_MCFC);
  int* MCFA = (int*)(ws + OFF_MCFA);
  int* MCFL = (int*)(ws + OFF_MCFL);

  // ~124 KB static LDS: functional + forces 1 block/CU (exclusive residency).
  __shared__ float xbuf[32 * 648];     // 82.9 KB: C's h stash (stride 648:
                                       // 16B-aligned per row, conflict-free)
  __shared__ float red[16 * 16 * 33];  // 33.8 KB partial sums
  __shared__ float aux[32 * 33];       // A: z rows; L: logit tile; C: gates
  __shared__ u64 kred[32 * 9];
  __shared__ float sered[32 * 9];
  __shared__ float c_lds[8 * 33], h_lds[8 * 33];
  __shared__ float sc_lds[32];
  __shared__ int tok_lds[32], nb_lds[32], lt_lds[32];

  const int bid = blockIdx.x, tid = threadIdx.x;
  const int dq = tid >> 4, bp = tid & 15; // 16 d-groups x 16 b-pairs (unique x)
  const int d0 = dq * 40, b0 = bp * 2;

  if (bid < NA) {
    // ---- stage A: XZ = tanh(W_tn.tn_t + W_pn.h + b_joint), 8 j rows ----
    const int j0 = bid * 8;
    const int* myFC = MCFC + (size_t)bid * 320; // my 80 private FC slots
    for (int t = 0; t < TT; ++t) {
      const int par = t & 1;
      // (1) Wtn part BEFORE waiting for h: immutable input, hides tn latency.
      float acc[8][2] = {};
      const float* t0p = tn + ((size_t)b0 * TT + t) * DD + d0;
      const float* t1p = t0p + (size_t)TT * DD;
#pragma unroll 5
      for (int q = 0; q < 10; ++q) {
        float4 x0 = *(const float4*)(t0p + q * 4);
        float4 x1 = *(const float4*)(t1p + q * 4);
        const float4* wt = (const float4*)WTN + (size_t)((d0 + q * 4) >> 2) * DD + j0;
#pragma unroll
        for (int r = 0; r < 8; ++r) {
          fma4(acc[r][0], wt[r], x0);
          fma4(acc[r][1], wt[r], x1);
        }
      }
      // (2) wait for h(t): all 80 C producers, private slots
      wait_mc(myFC, NC, t);
      // (3) Wpn part
      const float* h0p = XH + (size_t)par * 20480 + (size_t)b0 * DD + d0;
      const float* h1p = h0p + DD;
#pragma unroll 5
      for (int q = 0; q < 10; ++q) {
        float2 a0 = cload2(h0p + q * 4), a1 = cload2(h0p + q * 4 + 2);
        float2 b1 = cload2(h1p + q * 4), b2 = cload2(h1p + q * 4 + 2);
        const float4* wp = (const float4*)WPN + (size_t)((d0 + q * 4) >> 2) * DD + j0;
#pragma unroll
        for (int r = 0; r < 8; ++r) {
          fma22(acc[r][0], wp[r], a0, a1);
          fma22(acc[r][1], wp[r], b1, b2);
        }
      }
#pragma unroll
      for (int r = 0; r < 8; ++r) {
        red[(dq * 8 + r) * 33 + b0] = acc[r][0];
        red[(dq * 8 + r) * 33 + b0 + 1] = acc[r][1];
      }
      __syncthreads();
      {
        int r = tid >> 5, b = tid & 31;
        float s = 0.f;
#pragma unroll
        for (int k = 0; k < 16; ++k) s += red[(k * 8 + r) * 33 + b];
        aux[r * 33 + b] = tanhf(s + bj[j0 + r]);
      }
      __syncthreads();
      if (tid < 128) {
        int jp = tid >> 5, b = tid & 31;
        cstore2(XZ + (size_t)b * DD + j0 + jp * 2, aux[(jp * 2) * 33 + b],
                aux[(jp * 2 + 1) * 33 + b]);
      }
      publish_mc(MCFA, NL, NA, bid, t + 1);
    }
  } else if (bid < NA + NL) {
    // ---- stage L: 16-v logit tile -> per-block slots (zero-RMW) ----
    const int lb = bid - NA, v0 = lb * 16;
    const int* myFA = MCFA + (size_t)lb * 320; // my 80 private FA slots
    for (int t = 0; t < TT; ++t) {
      wait_mc(myFA, NA, t + 1);
      const float* z0p = XZ + (size_t)b0 * DD + d0;
      const float* z1p = z0p + DD;
      float acc[16][2] = {};
#pragma unroll 5
      for (int q = 0; q < 10; ++q) {
        float2 z0a = cload2(z0p + q * 4), z0b = cload2(z0p + q * 4 + 2);
        float2 z1a = cload2(z1p + q * 4), z1b = cload2(z1p + q * 4 + 2);
        const float4* wo = (const float4*)WOUT + (size_t)((d0 + q * 4) >> 2) * VV + v0;
#pragma unroll
        for (int r = 0; r < 16; ++r) {
          float4 w = wo[r];
          fma22(acc[r][0], w, z0a, z0b);
          fma22(acc[r][1], w, z1a, z1b);
        }
      }
#pragma unroll
      for (int r = 0; r < 16; ++r) {
        red[(dq * 16 + r) * 33 + b0] = acc[r][0];
        red[(dq * 16 + r) * 33 + b0 + 1] = acc[r][1];
      }
      __syncthreads();
#pragma unroll
      for (int o = tid; o < 512; o += 256) {
        int r = o >> 5, b = o & 31;
        float s = bo[v0 + r];
#pragma unroll
        for (int k = 0; k < 16; ++k) s += red[(k * 16 + r) * 33 + b];
        aux[r * 33 + b] = s;
      }
      __syncthreads();
      if (tid < 32) {
        int b = tid;
        float m = -1e30f, se = 0.f;
        int vbest = 0;
#pragma unroll
        for (int r = 0; r < 16; ++r) {
          float x = aux[r * 33 + b];
          se += expf(x);
          if (x > m) { m = x; vbest = r; } // strict > => first occurrence
        }
        u64 key = ((u64)ordf(m) << 32) | (u64)(0xFFFFFFFFu - (u32)(v0 + vbest));
        cstoreu64(&LKEY[(size_t)b * 64 + lb], key);
        cstoref(&LSE[(size_t)b * 64 + lb], se);
      }
      publish_mc(MCFL, NC, NL, lb, t + 1);
    }
  } else {
    // ---- stage C: gates = W_hh.h (LDS-stashed h, 2 passes of 16 rows),
    //      slot-reduce argmax, decode, LSTM elementwise ----
    const int cb = bid - (NA + NL), j0 = cb * 8;
    const int* myFC = MCFC + (size_t)(NA + cb) * 320; // my 80 private FC slots
    const int* myFL = MCFL + (size_t)cb * 256;        // my 64 private FL slots
    {
      int jj = tid >> 5, b = tid & 31, j = j0 + jj;
      float gi = P[j] + bl[j];
      float gg = P[1280 + j] + bl[1280 + j];
      float go = P[1920 + j] + bl[1920 + j];
      float c1 = sigf(gi) * tanhf(gg);
      c_lds[jj * 33 + b] = c1;
      h_lds[jj * 33 + b] = sigf(go) * tanhf(c1);
    }
    if (tid < 32) { lt_lds[tid] = 0; sc_lds[tid] = 0.f; }
    __syncthreads();
    for (int t = 0; t < TT; ++t) {
      const int par = t & 1;
      wait_mc(myFC, NC, t); // h(t) ready
      // stash h into LDS once (coherent reads, unique coverage)
      {
        const float* h0p = XH + (size_t)par * 20480 + (size_t)b0 * DD + d0;
        const float* h1p = h0p + DD;
#pragma unroll 5
        for (int q = 0; q < 10; ++q) {
          float2 a0 = cload2(h0p + q * 4), a1 = cload2(h0p + q * 4 + 2);
          float2 b1 = cload2(h1p + q * 4), b2 = cload2(h1p + q * 4 + 2);
          *(float4*)&xbuf[b0 * 648 + d0 + q * 4] = make_float4(a0.x, a0.y, a1.x, a1.y);
          *(float4*)&xbuf[(b0 + 1) * 648 + d0 + q * 4] = make_float4(b1.x, b1.y, b2.x, b2.y);
        }
      }
      __syncthreads();
#pragma unroll
      for (int p = 0; p < 2; ++p) {
        float acc[16][2] = {};
#pragma unroll 5
        for (int q = 0; q < 10; ++q) {
          const int d = d0 + q * 4;
          float4 h0 = *(const float4*)&xbuf[b0 * 648 + d];
          float4 h1 = *(const float4*)&xbuf[(b0 + 1) * 648 + d];
          const float4* wa =
              (const float4*)WHH + (size_t)(d >> 2) * GG + (2 * p) * DD + j0;
          const float4* wb = wa + DD;
#pragma unroll
          for (int jj = 0; jj < 8; ++jj) {
            fma4(acc[jj][0], wa[jj], h0);
            fma4(acc[jj][1], wa[jj], h1);
            fma4(acc[8 + jj][0], wb[jj], h0);
            fma4(acc[8 + jj][1], wb[jj], h1);
          }
        }
#pragma unroll
        for (int r = 0; r < 16; ++r) {
          red[(dq * 16 + r) * 33 + b0] = acc[r][0];
          red[(dq * 16 + r) * 33 + b0 + 1] = acc[r][1];
        }
        __syncthreads();
#pragma unroll
        for (int o = tid; o < 512; o += 256) {
          int r16 = o >> 5, b = o & 31;
          float s = 0.f;
#pragma unroll
          for (int k = 0; k < 16; ++k) s += red[(k * 16 + r16) * 33 + b];
          int g = 2 * p + (r16 >> 3), jj = r16 & 7;
          aux[(g * 8 + jj) * 33 + b] = s; // gates
        }
        __syncthreads();
      }
      wait_mc(myFL, NL, t + 1); // logits(t) ready
      // tree-reduce per-block argmax/sumexp slots (coalesced, deterministic)
      {
        int b = tid >> 3, ch = tid & 7;
        const u64* kp = LKEY + (size_t)b * 64 + ch * 8;
        u64 km = 0;
#pragma unroll
        for (int i = 0; i < 8; ++i) {
          u64 x = cloadu64(kp + i);
          km = x > km ? x : km;
        }
        kred[b * 9 + ch] = km;
        if (cb == 0) {
          const float* sp = LSE + (size_t)b * 64 + ch * 8;
          float ss = 0.f;
#pragma unroll
          for (int i = 0; i < 8; ++i) ss += cloadf(sp + i);
          sered[b * 9 + ch] = ss;
        }
      }
      __syncthreads();
      if (tid < 32) {
        int b = tid;
        u64 km = 0;
#pragma unroll
        for (int ch = 0; ch < 8; ++ch) {
          u64 x = kred[b * 9 + ch];
          km = x > km ? x : km;
        }
        u32 ou = (u32)(km >> 32);
        u32 fb = (ou & 0x80000000u) ? (ou & 0x7FFFFFFFu) : ~ou;
        float m = __uint_as_float(fb);
        int v = (int)(0xFFFFFFFFu - (u32)(km & 0xFFFFFFFFull));
        int nb = (v != 0) ? 1 : 0;
        int tok = nb ? v : lt_lds[b];
        lt_lds[b] = tok;
        tok_lds[b] = tok;
        nb_lds[b] = nb;
        if (cb == 0) {
          float S = 0.f;
#pragma unroll
          for (int ch = 0; ch < 8; ++ch) S += sered[b * 9 + ch];
          float lp = m - logf(S); // logits bounded: no max-shift needed
          if (nb) sc_lds[b] += lp;
          out[(size_t)b * TT + t] = nb ? (float)v : 0.0f;
          if (t == TT - 1) SCg[b] = sc_lds[b];
        }
      }
      __syncthreads();
      {
        int jj = tid >> 5, b = tid & 31, j = j0 + jj;
        if (nb_lds[b]) {
          const float* Pr = P + (size_t)tok_lds[b] * GG;
          float gi = aux[(0 + jj) * 33 + b] + Pr[j] + bl[j];
          float gf = aux[(8 + jj) * 33 + b] + Pr[640 + j] + bl[640 + j];
          float gg = aux[(16 + jj) * 33 + b] + Pr[1280 + j] + bl[1280 + j];
          float go = aux[(24 + jj) * 33 + b] + Pr[1920 + j] + bl[1920 + j];
          float c = c_lds[jj * 33 + b];
          float cn = sigf(gf) * c + sigf(gi) * tanhf(gg);
          float hn = sigf(go) * tanhf(cn);
          c_lds[jj * 33 + b] = cn;
          h_lds[jj * 33 + b] = hn;
        }
      }
      __syncthreads();
      if (tid < 128) {
        int jp = tid >> 5, b = tid & 31;
        cstore2(XH + (size_t)(1 - par) * 20480 + (size_t)b * DD + j0 + jp * 2,
                h_lds[(jp * 2) * 33 + b], h_lds[(jp * 2 + 1) * 33 + b]);
      }
      publish_mc(MCFC, NA + NC, NC, cb, t + 1);
    }
  }
}

__global__ __launch_bounds__(64) void k_final(const float* __restrict__ ws,
                                              float* __restrict__ out) {
  __shared__ float sh[32];
  int t = threadIdx.x;
  if (t < 32) {
    float s = ws[OFF_SC + t];
    out[32000 + t] = s;
    sh[t] = expf(s);
  }
  __syncthreads();
  if (t == 0) {
    float a = 0.f;
    for (int i = 0; i < 32; ++i) a += sh[i];
    out[32032] = a / 32.0f;
  }
}

extern "C" void kernel_launch(void* const* d_in, const int* in_sizes, int n_in,
                              void* d_out, int out_size, void* d_ws, size_t ws_size,
                              hipStream_t stream) {
  const float* tn = (const float*)d_in[0];
  const float* E = (const float*)d_in[1];
  const float* Wih = (const float*)d_in[2];
  const float* Whh = (const float*)d_in[3];
  const float* bl = (const float*)d_in[4];
  const float* Wtn = (const float*)d_in[5];
  const float* Wpn = (const float*)d_in[6];
  const float* bj = (const float*)d_in[7];
  const float* Wout = (const float*)d_in[8];
  const float* bo = (const float*)d_in[9];
  float* ws = (float*)d_ws;
  float* out = (float*)d_out;

  k_wt4<<<100, 256, 0, stream>>>(Wtn, ws + OFF_WTN, DD);
  k_wt4<<<100, 256, 0, stream>>>(Wpn, ws + OFF_WPN, DD);
  k_wt4<<<400, 256, 0, stream>>>(Whh, ws + OFF_WHH, GG);
  k_wt4<<<160, 256, 0, stream>>>(Wout, ws + OFF_WOUT, VV);
  k_pgemm<<<640, 256, 0, stream>>>(E, Wih, ws + OFF_P);
  k_init<<<4, 256, 0, stream>>>(ws, bl);
  k_decode<<<NBLK, 256, 0, stream>>>(ws, tn, bl, bj, bo, out);
  k_final<<<1, 64, 0, stream>>>(ws, out);
}